// Round 13
// baseline (1856.328 us; speedup 1.0000x reference)
//
#include <hip/hip_runtime.h>

#define NN 512
#define NM1 511
#define PCT(r, j) pcT[(r) * 13 + (j)]

// X-macros: T4x32(X) expands X(K,M) for K=0..3 (row group), M=0..31 (col)
#define T32(X, K) X(K,0) X(K,1) X(K,2) X(K,3) X(K,4) X(K,5) X(K,6) X(K,7) \
  X(K,8) X(K,9) X(K,10) X(K,11) X(K,12) X(K,13) X(K,14) X(K,15) \
  X(K,16) X(K,17) X(K,18) X(K,19) X(K,20) X(K,21) X(K,22) X(K,23) \
  X(K,24) X(K,25) X(K,26) X(K,27) X(K,28) X(K,29) X(K,30) X(K,31)
#define T4x32(X) T32(X,0) T32(X,1) T32(X,2) T32(X,3)
#define T32S(X) X(0) X(1) X(2) X(3) X(4) X(5) X(6) X(7) \
  X(8) X(9) X(10) X(11) X(12) X(13) X(14) X(15) \
  X(16) X(17) X(18) X(19) X(20) X(21) X(22) X(23) \
  X(24) X(25) X(26) X(27) X(28) X(29) X(30) X(31)
#define P8(X, K) X(K,0) X(K,1) X(K,2) X(K,3) X(K,4) X(K,5) X(K,6) X(K,7)
#define P4x8(X) P8(X,0) P8(X,1) P8(X,2) P8(X,3)

// readlane: value of v at (uniform) lane l -> scalar
__device__ __forceinline__ float rdlane(float v, int l) {
  return __uint_as_float(
      (unsigned)__builtin_amdgcn_readlane((int)__float_as_uint(v), l));
}

// One block per matrix (1024 blocks), 512 threads (8 waves), 1 block/CU via
// LDS pad -> 256-reg/thread budget. Blocked LU, panel r=8, redundant
// in-register panel factorization. r12 algebra (U-solve merged into trailing
// via L' = L*M^-1, no lbuf) kept; r13 fixes r12's NON-DETERMINISM: barriers
// were inside wave-divergent branches (convergent-op UB -> compiler may
// reorder LDS ops around them). Both barriers are now at workgroup-uniform
// top level; factor/trailing phases are separate uniform-guarded regions.
__global__ __launch_bounds__(512, 2) void det_lu_kernel(
    const float* __restrict__ x,
    const float* __restrict__ F,
    float* __restrict__ out) {
  __shared__ __align__(16) float pcT[256 * 13];   // panel cols, row-major pad 13
  __shared__ __align__(16) float Ubuf[8 * 260];   // raw pivot rows (stash)
  __shared__ float livef[256];
  __shared__ int   perm[256];
  __shared__ int   upbuf[256];
  __shared__ int   dnbuf[256];
  __shared__ int   wavecnt[8];
  __shared__ int   totinv;
  __shared__ float ldspad[14100];   // LDS > 80KiB -> exactly 1 block/CU

  const int tid = threadIdx.x;
  const int L   = tid & 63;       // lane
  const int w   = tid >> 6;       // wave, owns cols [32w, 32w+32)

  const float* xrow = x + (size_t)blockIdx.x * NN;

  // keep ldspad referenced (opaque never-true condition)
  if ((int)blockIdx.x < 0) ((volatile float*)ldspad)[tid] = 1.0f;

  // ---- rank the +/-1 pattern: up = x>0 positions, dn = x<=0 positions
  float xv = xrow[tid];            // 512 threads == NN
  bool pos = xv > 0.0f;
  unsigned long long mask = __ballot(pos);
  if (L == 0) wavecnt[w] = __popcll(mask);
  if (tid == 0) totinv = 0;
  if (tid < 256) livef[tid] = 1.0f;
  __syncthreads();
  {
    int base = 0;
    for (int i = 0; i < w; i++) base += wavecnt[i];
    int pbelow = __popcll(mask & ((1ull << L) - 1ull));
    if (pos) upbuf[base + pbelow] = tid;
    else     dnbuf[(64 * w - base) + (L - pbelow)] = tid;
  }
  __syncthreads();

  // ---- gather tile into 128 named scalars: aK_M = sub[L+64K][32w+M]
#define DECLC(M) const int cg##M = dnbuf[32 * w + (M)];
  T32S(DECLC)
  const int rg0 = upbuf[L];
  const int rg1 = upbuf[L + 64];
  const int rg2 = upbuf[L + 128];
  const int rg3 = upbuf[L + 192];
#define DECLA(K, M)                                                         \
  float a##K##_##M = (cg##M == rg##K)                                       \
      ? 0.0f                                                                \
      : F[(size_t)rg##K * NM1 + cg##M - (cg##M > rg##K ? 1 : 0)];
  T4x32(DECLA)

  // ---- seed panel 0: wave 0 writes PCT[row][0..7]
  if (w == 0) {
#define S0(K, M) if ((M) < 8) PCT(L + 64 * (K), (M)) = a##K##_##M;
    T4x32(S0)
  }
  double det = 1.0;
  __syncthreads();   // barrier A (panel 0 seeded)

  // ======================= panel factor-step machinery =====================
#define DPPMAX(CTRL) {                                                      \
    unsigned _t = (unsigned)__builtin_amdgcn_update_dpp(                    \
        0, (int)key, (CTRL), 0xf, 0xf, false);                              \
    key = key > _t ? key : _t; }
#define BCJ(K, J, S) if ((J) >= (S)) uv##J = rdlane(pr##K##_##J, lp);
#define BCARM(K, S)                                                         \
    if (kp == (K)) { BCJ(K,0,S) BCJ(K,1,S) BCJ(K,2,S) BCJ(K,3,S)            \
                     BCJ(K,4,S) BCJ(K,5,S) BCJ(K,6,S) BCJ(K,7,S) }
#define LSTEP(K, S)                                                         \
    float l##K = ((dead4 >> (K)) & 1u) ? 0.0f : pr##K##_##S * invp;         \
    pr##K##_##S = l##K;
#define UPD(K, J, S)                                                        \
    if ((J) > (S)) pr##K##_##J = fmaf(-l##K, uv##J, pr##K##_##J);
#define UPDJ(J, S) UPD(0,J,S) UPD(1,J,S) UPD(2,J,S) UPD(3,J,S)
#define STQ(K, Q, M0, M1, M2, M3)                                           \
    if (kp == (K)) *reinterpret_cast<float4*>(&Ubuf[sb + 4 * (Q)]) =        \
        make_float4(a##K##_##M0, a##K##_##M1, a##K##_##M2, a##K##_##M3);
#define STHK(K)                                                             \
    STQ(K,0,0,1,2,3) STQ(K,1,4,5,6,7) STQ(K,2,8,9,10,11)                    \
    STQ(K,3,12,13,14,15) STQ(K,4,16,17,18,19) STQ(K,5,20,21,22,23)          \
    STQ(K,6,24,25,26,27) STQ(K,7,28,29,30,31)
#define FSTEP(S) {                                                          \
    unsigned b0 = (dead4 & 1u) ? 0u                                         \
        : ((__float_as_uint(fabsf(pr0_##S)) & 0xFFFFFF00u) | (unsigned)L);  \
    unsigned b1 = (dead4 & 2u) ? 0u                                         \
        : ((__float_as_uint(fabsf(pr1_##S)) & 0xFFFFFF00u) | (unsigned)(L + 64)); \
    unsigned b2 = (dead4 & 4u) ? 0u                                         \
        : ((__float_as_uint(fabsf(pr2_##S)) & 0xFFFFFF00u) | (unsigned)(L + 128)); \
    unsigned b3 = (dead4 & 8u) ? 0u                                         \
        : ((__float_as_uint(fabsf(pr3_##S)) & 0xFFFFFF00u) | (unsigned)(L + 192)); \
    unsigned m01 = b0 > b1 ? b0 : b1, m23 = b2 > b3 ? b2 : b3;              \
    unsigned key = m01 > m23 ? m01 : m23;                                   \
    DPPMAX(0x111) DPPMAX(0x112) DPPMAX(0x114) DPPMAX(0x118)                 \
    DPPMAX(0x142) DPPMAX(0x143)                                             \
    const int pv = __builtin_amdgcn_readlane((int)key, 63) & 255;           \
    const int kp = pv >> 6, lp = pv & 63;                                   \
    kp##S = kp; lp##S = lp;                                                 \
    if (lp == L) dead4 |= 1u << kp;                                         \
    float uv0 = 0.f, uv1 = 0.f, uv2 = 0.f, uv3 = 0.f;                       \
    float uv4 = 0.f, uv5 = 0.f, uv6 = 0.f, uv7 = 0.f;                       \
    BCARM(0,S) BCARM(1,S) BCARM(2,S) BCARM(3,S)                             \
    const float piv = uv##S;                                                \
    det *= (double)piv;                                                     \
    const float invp = 1.0f / piv;                                          \
    LSTEP(0,S) LSTEP(1,S) LSTEP(2,S) LSTEP(3,S)                             \
    UPDJ(0,S) UPDJ(1,S) UPDJ(2,S) UPDJ(3,S)                                 \
    UPDJ(4,S) UPDJ(5,S) UPDJ(6,S) UPDJ(7,S)                                 \
    if (w == 0) {                                                           \
      if (L == lp) livef[pv] = 0.0f;                                        \
      if (L == 0) perm[P * 8 + (S)] = pv;                                   \
    }                                                                       \
    if (trailing && L == lp) {                                              \
      const int sb = (S) * 260 + 32 * w;                                    \
      STHK(0) STHK(1) STHK(2) STHK(3)                                       \
    }                                                                       \
  }

  // c[t][s] = l_t[p_s] extraction (t < s), wave-uniform via readlane
#define GC(K,T,S) c##T##_##S = rdlane(pr##K##_##T, lp##S);
#define GC1(K) GC(K,0,1)
#define GC2(K) GC(K,0,2) GC(K,1,2)
#define GC3(K) GC(K,0,3) GC(K,1,3) GC(K,2,3)
#define GC4(K) GC(K,0,4) GC(K,1,4) GC(K,2,4) GC(K,3,4)
#define GC5(K) GC(K,0,5) GC(K,1,5) GC(K,2,5) GC(K,3,5) GC(K,4,5)
#define GC6(K) GC(K,0,6) GC(K,1,6) GC(K,2,6) GC(K,3,6) GC(K,4,6) GC(K,5,6)
#define GC7(K) GC(K,0,7) GC(K,1,7) GC(K,2,7) GC(K,3,7) GC(K,4,7) GC(K,5,7) GC(K,6,7)
#define SELK(S, GCn)                                                        \
    if      (kp##S == 0) { GCn(0) }                                         \
    else if (kp##S == 1) { GCn(1) }                                         \
    else if (kp##S == 2) { GCn(2) }                                         \
    else                 { GCn(3) }

  // in-place downward L'-solve: pr_t -= sum_{s>t} pr_s * c[t][s]
#define LSOLVE(K)                                                           \
    pr##K##_6 = fmaf(-pr##K##_7, c6_7, pr##K##_6);                          \
    pr##K##_5 = fmaf(-pr##K##_6, c5_6, pr##K##_5);                          \
    pr##K##_5 = fmaf(-pr##K##_7, c5_7, pr##K##_5);                          \
    pr##K##_4 = fmaf(-pr##K##_5, c4_5, pr##K##_4);                          \
    pr##K##_4 = fmaf(-pr##K##_6, c4_6, pr##K##_4);                          \
    pr##K##_4 = fmaf(-pr##K##_7, c4_7, pr##K##_4);                          \
    pr##K##_3 = fmaf(-pr##K##_4, c3_4, pr##K##_3);                          \
    pr##K##_3 = fmaf(-pr##K##_5, c3_5, pr##K##_3);                          \
    pr##K##_3 = fmaf(-pr##K##_6, c3_6, pr##K##_3);                          \
    pr##K##_3 = fmaf(-pr##K##_7, c3_7, pr##K##_3);                          \
    pr##K##_2 = fmaf(-pr##K##_3, c2_3, pr##K##_2);                          \
    pr##K##_2 = fmaf(-pr##K##_4, c2_4, pr##K##_2);                          \
    pr##K##_2 = fmaf(-pr##K##_5, c2_5, pr##K##_2);                          \
    pr##K##_2 = fmaf(-pr##K##_6, c2_6, pr##K##_2);                          \
    pr##K##_2 = fmaf(-pr##K##_7, c2_7, pr##K##_2);                          \
    pr##K##_1 = fmaf(-pr##K##_2, c1_2, pr##K##_1);                          \
    pr##K##_1 = fmaf(-pr##K##_3, c1_3, pr##K##_1);                          \
    pr##K##_1 = fmaf(-pr##K##_4, c1_4, pr##K##_1);                          \
    pr##K##_1 = fmaf(-pr##K##_5, c1_5, pr##K##_1);                          \
    pr##K##_1 = fmaf(-pr##K##_6, c1_6, pr##K##_1);                          \
    pr##K##_1 = fmaf(-pr##K##_7, c1_7, pr##K##_1);                          \
    pr##K##_0 = fmaf(-pr##K##_1, c0_1, pr##K##_0);                          \
    pr##K##_0 = fmaf(-pr##K##_2, c0_2, pr##K##_0);                          \
    pr##K##_0 = fmaf(-pr##K##_3, c0_3, pr##K##_0);                          \
    pr##K##_0 = fmaf(-pr##K##_4, c0_4, pr##K##_0);                          \
    pr##K##_0 = fmaf(-pr##K##_5, c0_5, pr##K##_0);                          \
    pr##K##_0 = fmaf(-pr##K##_6, c0_6, pr##K##_0);                          \
    pr##K##_0 = fmaf(-pr##K##_7, c0_7, pr##K##_0);

  // trailing: A_K_M -= sum_t pr_K_t * raw[t][M]
#define TUROW(K, T, A, B, C, D)                                             \
    a##K##_##A = fmaf(-pr##K##_##T, uq.x, a##K##_##A);                      \
    a##K##_##B = fmaf(-pr##K##_##T, uq.y, a##K##_##B);                      \
    a##K##_##C = fmaf(-pr##K##_##T, uq.z, a##K##_##C);                      \
    a##K##_##D = fmaf(-pr##K##_##T, uq.w, a##K##_##D);
#define TUQn(T, A, B, C, D)                                                 \
    TUROW(0, T, A, B, C, D) TUROW(1, T, A, B, C, D)                         \
    TUROW(2, T, A, B, C, D) TUROW(3, T, A, B, C, D)
#define TUT(T) {                                                            \
    const float* ub = &Ubuf[(T) * 260 + 32 * w];                            \
    { const float4 uq = *reinterpret_cast<const float4*>(ub + 0);           \
      TUQn(T, 0, 1, 2, 3) }                                                 \
    { const float4 uq = *reinterpret_cast<const float4*>(ub + 4);           \
      TUQn(T, 4, 5, 6, 7) }                                                 \
    { const float4 uq = *reinterpret_cast<const float4*>(ub + 8);           \
      TUQn(T, 8, 9, 10, 11) }                                               \
    { const float4 uq = *reinterpret_cast<const float4*>(ub + 12);          \
      TUQn(T, 12, 13, 14, 15) }                                             \
    { const float4 uq = *reinterpret_cast<const float4*>(ub + 16);          \
      TUQn(T, 16, 17, 18, 19) }                                             \
    { const float4 uq = *reinterpret_cast<const float4*>(ub + 20);          \
      TUQn(T, 20, 21, 22, 23) }                                             \
    { const float4 uq = *reinterpret_cast<const float4*>(ub + 24);          \
      TUQn(T, 24, 25, 26, 27) }                                             \
    { const float4 uq = *reinterpret_cast<const float4*>(ub + 28);          \
      TUQn(T, 28, 29, 30, 31) }                                             \
  }

  // ---- panel loop (barriers at workgroup-uniform top level ONLY)
#pragma unroll 1
  for (int P = 0; P < 32; P++) {
    const bool trailing  = (4 * w + 3 > P);      // wave-uniform
    const bool factoring = trailing || (w == 0); // wave-uniform
    int kp1, lp1, kp2, lp2, kp3, lp3, kp4, lp4;
    int kp5, lp5, kp6, lp6, kp7, lp7;
    int kp0, lp0;
    (void)kp0; (void)lp0;
    // panel registers: declared at panel scope, loaded only by factoring
#define DPR(K, J) float pr##K##_##J;
    P4x8(DPR)

    if (factoring) {
#define LDPA(K, J) pr##K##_##J = PCT(L + 64 * (K), (J));
      P4x8(LDPA)
      unsigned dead4 = 0u;
      // 8 in-register column-steps: no barriers, no LDS reads
      FSTEP(0) FSTEP(1) FSTEP(2) FSTEP(3)
      FSTEP(4) FSTEP(5) FSTEP(6) FSTEP(7)
    }

    __syncthreads();   // barrier B (uniform): stash/livef/perm visible

    if (trailing) {
      // wave-uniform M entries via readlane from pivot lanes' pr regs
      float c0_1, c0_2, c1_2, c0_3, c1_3, c2_3, c0_4, c1_4, c2_4, c3_4,
            c0_5, c1_5, c2_5, c3_5, c4_5,
            c0_6, c1_6, c2_6, c3_6, c4_6, c5_6,
            c0_7, c1_7, c2_7, c3_7, c4_7, c5_7, c6_7;
      SELK(1, GC1) SELK(2, GC2) SELK(3, GC3) SELK(4, GC4)
      SELK(5, GC5) SELK(6, GC6) SELK(7, GC7)
      // L' = L * M^-1 (in place, downward)
      LSOLVE(0) LSOLVE(1) LSOLVE(2) LSOLVE(3)
      // rank-8 trailing update against RAW pivot rows
      TUT(0) TUT(1) TUT(2) TUT(3) TUT(4) TUT(5) TUT(6) TUT(7)
    }

    // -------- seed next panel --------
    {
      const int wstar = (P + 1) >> 2, h = (P + 1) & 3;
      if (P < 31 && w == wstar) {
        const float lv0 = livef[L];
        const float lv1 = livef[L + 64];
        const float lv2 = livef[L + 128];
        const float lv3 = livef[L + 192];
#define SEa(K, M) if ((M) < 8)                PCT(L + 64*(K), (M))      = a##K##_##M * lv##K;
#define SEb(K, M) if ((M) >= 8 && (M) < 16)   PCT(L + 64*(K), (M) - 8)  = a##K##_##M * lv##K;
#define SEc(K, M) if ((M) >= 16 && (M) < 24)  PCT(L + 64*(K), (M) - 16) = a##K##_##M * lv##K;
#define SEd(K, M) if ((M) >= 24)              PCT(L + 64*(K), (M) - 24) = a##K##_##M * lv##K;
        if (h == 0)      { T4x32(SEa) }
        else if (h == 1) { T4x32(SEb) }
        else if (h == 2) { T4x32(SEc) }
        else             { T4x32(SEd) }
      }
    }
    __syncthreads();   // barrier A (uniform): next panel seeded
  }

  // ---- permutation parity via parallel inversion count (512-thread map)
  int myinv = 0;
  {
    const int i0 = tid & 255;
    const int cbase = (tid >> 8) * 128;
    const int pi = perm[i0];
#pragma unroll 8
    for (int j = 0; j < 128; j++) {
      int jj = cbase + j;
      if (jj > i0 && perm[jj] < pi) myinv++;
    }
  }
#pragma unroll
  for (int off = 32; off; off >>= 1) myinv += __shfl_xor(myinv, off);
  if (L == 0) atomicAdd(&totinv, myinv);
  __syncthreads();
  if (tid == 0) out[blockIdx.x] = (float)((totinv & 1) ? -det : det);
}

extern "C" void kernel_launch(void* const* d_in, const int* in_sizes, int n_in,
                              void* d_out, int out_size, void* d_ws, size_t ws_size,
                              hipStream_t stream) {
  const float* x = (const float*)d_in[0];   // (1024, 512) fp32
  const float* F = (const float*)d_in[1];   // (512*512-512,) fp32
  float* out = (float*)d_out;               // (1024,) fp32
  const int B = out_size;                   // 1024
  hipLaunchKernelGGL(det_lu_kernel, dim3(B), dim3(512), 0, stream, x, F, out);
}

// Round 14
// 977.386 us; speedup vs baseline: 1.8993x; 1.8993x over previous
//
#include <hip/hip_runtime.h>

#define NN 512
#define NM1 511
#define PCT(r, j) pcT[(r) * 13 + (j)]

// X-macros: T4x16(X) expands X(K,M) for K=0..3 (row group), M=0..15 (col)
#define T16(X, K) X(K,0) X(K,1) X(K,2) X(K,3) X(K,4) X(K,5) X(K,6) X(K,7) \
  X(K,8) X(K,9) X(K,10) X(K,11) X(K,12) X(K,13) X(K,14) X(K,15)
#define T4x16(X) T16(X,0) T16(X,1) T16(X,2) T16(X,3)
#define T16S(X) X(0) X(1) X(2) X(3) X(4) X(5) X(6) X(7) \
  X(8) X(9) X(10) X(11) X(12) X(13) X(14) X(15)
#define P8(X, K) X(K,0) X(K,1) X(K,2) X(K,3) X(K,4) X(K,5) X(K,6) X(K,7)
#define P4x8(X) P8(X,0) P8(X,1) P8(X,2) P8(X,3)

// readlane: value of v at (uniform) lane l -> scalar
__device__ __forceinline__ float rdlane(float v, int l) {
  return __uint_as_float(
      (unsigned)__builtin_amdgcn_readlane((int)__float_as_uint(v), l));
}

// One block per matrix (1024 blocks), 1024 THREADS (16 waves), 1 block/CU via
// LDS pad + waves_per_eu(4,4) -> 4 waves/SIMD, 128-reg/thread budget.
// r13 post-mortem: U-solve-merge algebra cost +74 live regs -> spill; revert
// to r11's verified dataflow (lbuf + LDS U-solve + 3 top-level barriers, DPP
// argmax, readlane broadcast). r11 @512thr was latency-bound at 2 waves/SIMD
// (VALUBusy 39%, occ 24%); this round re-tiles to 16 waves: tile = rows
// {L,L+64,L+128,L+192} x cols [16w,16w+16) = 64 named scalars -> working set
// ~115 <= 128 budget (r8 proved 64VGPR+64AGPR materializes at this config).
__global__ __attribute__((amdgpu_waves_per_eu(4, 4))) __launch_bounds__(1024)
void det_lu_kernel(
    const float* __restrict__ x,
    const float* __restrict__ F,
    float* __restrict__ out) {
  __shared__ __align__(16) float pcT[256 * 13];   // panel cols, row-major pad 13
  __shared__ __align__(16) float lbuf[8 * 256];   // multipliers per step
  __shared__ __align__(16) float Ubuf[8 * 260];   // raw-then-final pivot rows
  __shared__ float livef[256];
  __shared__ int   perm[256];
  __shared__ int   upbuf[256];
  __shared__ int   dnbuf[256];
  __shared__ int   wavecnt[8];
  __shared__ int   totinv;
  __shared__ float ldspad[12100];   // LDS > 80KiB -> exactly 1 block/CU

  const int tid = threadIdx.x;
  const int L   = tid & 63;       // lane
  const int w   = tid >> 6;       // wave, owns cols [16w, 16w+16)

  const float* xrow = x + (size_t)blockIdx.x * NN;

  // keep ldspad referenced (opaque never-true condition)
  if ((int)blockIdx.x < 0) ((volatile float*)ldspad)[tid] = 1.0f;

  // ---- rank the +/-1 pattern: up = x>0 positions, dn = x<=0 positions
  bool pos = false;
  unsigned long long mask = 0;
  if (tid < NN) {
    float xv = xrow[tid];
    pos = xv > 0.0f;
    mask = __ballot(pos);           // waves 0-7 fully active
    if (L == 0) wavecnt[w] = __popcll(mask);
  }
  if (tid == 0) totinv = 0;
  if (tid < 256) livef[tid] = 1.0f;
  __syncthreads();
  if (tid < NN) {
    int base = 0;
    for (int i = 0; i < w; i++) base += wavecnt[i];
    int pbelow = __popcll(mask & ((1ull << L) - 1ull));
    if (pos) upbuf[base + pbelow] = tid;
    else     dnbuf[(64 * w - base) + (L - pbelow)] = tid;
  }
  __syncthreads();

  // ---- gather tile into 64 named scalars: aK_M = sub[L+64K][16w+M]
#define DECLC(M) const int cg##M = dnbuf[16 * w + (M)];
  T16S(DECLC)
  const int rg0 = upbuf[L];
  const int rg1 = upbuf[L + 64];
  const int rg2 = upbuf[L + 128];
  const int rg3 = upbuf[L + 192];
#define DECLA(K, M)                                                         \
  float a##K##_##M = (cg##M == rg##K)                                       \
      ? 0.0f                                                                \
      : F[(size_t)rg##K * NM1 + cg##M - (cg##M > rg##K ? 1 : 0)];
  T4x16(DECLA)

  // ---- seed panel 0: wave 0 (owns cols 0..15) writes PCT[row][0..7]
  if (w == 0) {
#define S0(K, M) if ((M) < 8) PCT(L + 64 * (K), (M)) = a##K##_##M;
    T4x16(S0)
  }
  double det = 1.0;
  __syncthreads();   // barrier A (panel 0 seeded)

  // ======================= panel factor-step machinery =====================
#define DPPMAX(CTRL) {                                                      \
    unsigned _t = (unsigned)__builtin_amdgcn_update_dpp(                    \
        0, (int)key, (CTRL), 0xf, 0xf, false);                              \
    key = key > _t ? key : _t; }
#define BCJ(K, J, S) if ((J) >= (S)) uv##J = rdlane(pr##K##_##J, lp);
#define BCARM(K, S)                                                         \
    if (kp == (K)) { BCJ(K,0,S) BCJ(K,1,S) BCJ(K,2,S) BCJ(K,3,S)            \
                     BCJ(K,4,S) BCJ(K,5,S) BCJ(K,6,S) BCJ(K,7,S) }
#define LSTEP(K, S)                                                         \
    float l##K = ((dead4 >> (K)) & 1u) ? 0.0f : pr##K##_##S * invp;         \
    pr##K##_##S = l##K;
#define UPD(K, J, S)                                                        \
    if ((J) > (S)) pr##K##_##J = fmaf(-l##K, uv##J, pr##K##_##J);
#define UPDJ(J, S) UPD(0,J,S) UPD(1,J,S) UPD(2,J,S) UPD(3,J,S)
#define STQ(K, Q, M0, M1, M2, M3)                                           \
    if (kp == (K)) *reinterpret_cast<float4*>(&Ubuf[sb + 4 * (Q)]) =        \
        make_float4(a##K##_##M0, a##K##_##M1, a##K##_##M2, a##K##_##M3);
#define STHK(K)                                                             \
    STQ(K,0,0,1,2,3) STQ(K,1,4,5,6,7)                                       \
    STQ(K,2,8,9,10,11) STQ(K,3,12,13,14,15)
#define FSTEP(S) {                                                          \
    unsigned b0 = (dead4 & 1u) ? 0u                                         \
        : ((__float_as_uint(fabsf(pr0_##S)) & 0xFFFFFF00u) | (unsigned)L);  \
    unsigned b1 = (dead4 & 2u) ? 0u                                         \
        : ((__float_as_uint(fabsf(pr1_##S)) & 0xFFFFFF00u) | (unsigned)(L + 64)); \
    unsigned b2 = (dead4 & 4u) ? 0u                                         \
        : ((__float_as_uint(fabsf(pr2_##S)) & 0xFFFFFF00u) | (unsigned)(L + 128)); \
    unsigned b3 = (dead4 & 8u) ? 0u                                         \
        : ((__float_as_uint(fabsf(pr3_##S)) & 0xFFFFFF00u) | (unsigned)(L + 192)); \
    unsigned m01 = b0 > b1 ? b0 : b1, m23 = b2 > b3 ? b2 : b3;              \
    unsigned key = m01 > m23 ? m01 : m23;                                   \
    DPPMAX(0x111) DPPMAX(0x112) DPPMAX(0x114) DPPMAX(0x118)                 \
    DPPMAX(0x142) DPPMAX(0x143)                                             \
    const int pv = __builtin_amdgcn_readlane((int)key, 63) & 255;           \
    const int kp = pv >> 6, lp = pv & 63;                                   \
    if (lp == L) dead4 |= 1u << kp;                                         \
    float uv0 = 0.f, uv1 = 0.f, uv2 = 0.f, uv3 = 0.f;                       \
    float uv4 = 0.f, uv5 = 0.f, uv6 = 0.f, uv7 = 0.f;                       \
    BCARM(0,S) BCARM(1,S) BCARM(2,S) BCARM(3,S)                             \
    const float piv = uv##S;                                                \
    det *= (double)piv;                                                     \
    const float invp = 1.0f / piv;                                          \
    LSTEP(0,S) LSTEP(1,S) LSTEP(2,S) LSTEP(3,S)                             \
    UPDJ(0,S) UPDJ(1,S) UPDJ(2,S) UPDJ(3,S)                                 \
    UPDJ(4,S) UPDJ(5,S) UPDJ(6,S) UPDJ(7,S)                                 \
    if (w == 0) {                                                           \
      lbuf[(S) * 256 + L      ] = l0;                                       \
      lbuf[(S) * 256 + L +  64] = l1;                                       \
      lbuf[(S) * 256 + L + 128] = l2;                                       \
      lbuf[(S) * 256 + L + 192] = l3;                                       \
      if (L == lp) livef[pv] = 0.0f;                                        \
      if (L == 0) perm[P * 8 + (S)] = pv;                                   \
    }                                                                       \
    if (trailing && L == lp) {                                              \
      const int sb = (S) * 260 + 16 * w;                                    \
      STHK(0) STHK(1) STHK(2) STHK(3)                                       \
    }                                                                       \
  }

  // trailing: A_K_M -= sum_t lk_K[t] * U[t][M]
#define TUROW(K, A, B, C, D)                                                \
    a##K##_##A = fmaf(-lk##K, uq.x, a##K##_##A);                            \
    a##K##_##B = fmaf(-lk##K, uq.y, a##K##_##B);                            \
    a##K##_##C = fmaf(-lk##K, uq.z, a##K##_##C);                            \
    a##K##_##D = fmaf(-lk##K, uq.w, a##K##_##D);
#define TUQ(A, B, C, D)                                                     \
    TUROW(0, A, B, C, D) TUROW(1, A, B, C, D)                               \
    TUROW(2, A, B, C, D) TUROW(3, A, B, C, D)

  // ---- panel loop (barriers at workgroup-uniform top level ONLY)
#pragma unroll 1
  for (int P = 0; P < 32; P++) {
    const bool trailing  = (2 * w + 1 > P);      // wave-uniform
    const bool factoring = trailing || (w == 0); // wave-uniform

    if (factoring) {
      // load panel into regs (redundant per-wave copy of all 256 rows)
#define LDP(K, J) float pr##K##_##J = PCT(L + 64 * (K), (J));
      P4x8(LDP)
      unsigned dead4 = 0u;
      // 8 in-register column-steps: no barriers, no bpermute
      FSTEP(0) FSTEP(1) FSTEP(2) FSTEP(3)
      FSTEP(4) FSTEP(5) FSTEP(6) FSTEP(7)
    }
    __syncthreads();   // barrier B: lbuf/livef/perm + Ubuf raw stash visible

    // -------- U-solve: Ubuf[t][j] = raw[t][j] - sum_{s<t} l[s][p_t]*U[s][j]
    if (tid < 256) {
      const int j = tid;
      float u[8];
#pragma unroll
      for (int t = 0; t < 8; t++) {
        int pt = perm[P * 8 + t];
        float acc = Ubuf[t * 260 + j];           // raw (stashed in factor)
#pragma unroll
        for (int s2 = 0; s2 < t; s2++) acc = fmaf(-lbuf[s2 * 256 + pt], u[s2], acc);
        u[t] = acc;
        Ubuf[t * 260 + j] = acc;                 // final
      }
    }
    __syncthreads();   // barrier C: Ubuf final visible

    // -------- rank-8 trailing update + seed next panel --------
    if (trailing) {
#pragma unroll 1
      for (int t = 0; t < 8; t++) {
        const int lb = t * 256 + L;
        const float lk0 = lbuf[lb];
        const float lk1 = lbuf[lb + 64];
        const float lk2 = lbuf[lb + 128];
        const float lk3 = lbuf[lb + 192];
        const float* ub = &Ubuf[t * 260 + 16 * w];
        { const float4 uq = *reinterpret_cast<const float4*>(ub + 0);
          TUQ(0, 1, 2, 3) }
        { const float4 uq = *reinterpret_cast<const float4*>(ub + 4);
          TUQ(4, 5, 6, 7) }
        { const float4 uq = *reinterpret_cast<const float4*>(ub + 8);
          TUQ(8, 9, 10, 11) }
        { const float4 uq = *reinterpret_cast<const float4*>(ub + 12);
          TUQ(12, 13, 14, 15) }
      }
    }
    {
      const int wstar = (P + 1) >> 1, h = (P + 1) & 1;
      if (P < 31 && w == wstar) {
        const float lv0 = livef[L];
        const float lv1 = livef[L + 64];
        const float lv2 = livef[L + 128];
        const float lv3 = livef[L + 192];
#define SEa(K, M) if ((M) < 8)  PCT(L + 64*(K), (M))     = a##K##_##M * lv##K;
#define SEb(K, M) if ((M) >= 8) PCT(L + 64*(K), (M) - 8) = a##K##_##M * lv##K;
        if (h == 0) { T4x16(SEa) }
        else        { T4x16(SEb) }
      }
    }
    __syncthreads();   // barrier A: next panel seeded
  }

  // ---- permutation parity via parallel inversion count (1024-thread map)
  int myinv = 0;
  {
    const int i0 = tid & 255;
    const int cbase = (tid >> 8) * 64;
    const int pi = perm[i0];
#pragma unroll 8
    for (int j = 0; j < 64; j++) {
      int jj = cbase + j;
      if (jj > i0 && perm[jj] < pi) myinv++;
    }
  }
#pragma unroll
  for (int off = 32; off; off >>= 1) myinv += __shfl_xor(myinv, off);
  if (L == 0) atomicAdd(&totinv, myinv);
  __syncthreads();
  if (tid == 0) out[blockIdx.x] = (float)((totinv & 1) ? -det : det);
}

extern "C" void kernel_launch(void* const* d_in, const int* in_sizes, int n_in,
                              void* d_out, int out_size, void* d_ws, size_t ws_size,
                              hipStream_t stream) {
  const float* x = (const float*)d_in[0];   // (1024, 512) fp32
  const float* F = (const float*)d_in[1];   // (512*512-512,) fp32
  float* out = (float*)d_out;               // (1024,) fp32
  const int B = out_size;                   // 1024
  hipLaunchKernelGGL(det_lu_kernel, dim3(B), dim3(1024), 0, stream, x, F, out);
}